// Round 1
// baseline (41.537 us; speedup 1.0000x reference)
//
#include <hip/hip_runtime.h>
#include <math.h>

constexpr int BATCH  = 128;
constexpr int LABELS = 512;
constexpr int DIM    = 1024;
constexpr int ROWS   = BATCH * LABELS;        // 65536 output elements
constexpr int WAVES_PER_BLOCK = 4;            // 256 threads

__global__ __launch_bounds__(256) void
labelwise_mlc_kernel(const float* __restrict__ doc,
                     const float* __restrict__ W,
                     const float* __restrict__ bias,
                     float* __restrict__ out)
{
    const int wave = threadIdx.x >> 6;                    // 0..3
    const int lane = threadIdx.x & 63;                    // 0..63
    const int row  = blockIdx.x * WAVES_PER_BLOCK + wave; // 0..65535
    if (row >= ROWS) return;

    const int l = row & (LABELS - 1);                     // label index

    const float4* dp = reinterpret_cast<const float4*>(doc + (size_t)row * DIM);
    const float4* wp = reinterpret_cast<const float4*>(W   + (size_t)l   * DIM);

    // 1024 floats = 256 float4; 64 lanes x 4 iters, stride 64 float4 (coalesced 1KiB/instr)
    float acc = 0.0f;
#pragma unroll
    for (int j = 0; j < 4; ++j) {
        const float4 a = dp[lane + j * 64];
        const float4 w = wp[lane + j * 64];
        acc += a.x * w.x + a.y * w.y + a.z * w.z + a.w * w.w;
    }

    // butterfly reduce across the 64-lane wave
#pragma unroll
    for (int off = 32; off >= 1; off >>= 1)
        acc += __shfl_xor(acc, off, 64);

    if (lane == 0) {
        const float x = acc + bias[l];
        out[row] = 1.0f / (1.0f + expf(-x));
    }
}

extern "C" void kernel_launch(void* const* d_in, const int* in_sizes, int n_in,
                              void* d_out, int out_size, void* d_ws, size_t ws_size,
                              hipStream_t stream)
{
    const float* doc  = (const float*)d_in[0];  // [128, 512, 1024] f32
    const float* W    = (const float*)d_in[1];  // [512, 1024] f32
    const float* bias = (const float*)d_in[2];  // [512] f32
    float* out        = (float*)d_out;          // [128, 512] f32

    const int blocks = ROWS / WAVES_PER_BLOCK;  // 16384
    labelwise_mlc_kernel<<<blocks, 256, 0, stream>>>(doc, W, bias, out);
}